// Round 14
// baseline (60.452 us; speedup 1.0000x reference)
//
#include <hip/hip_runtime.h>

// Laplacian pyramid loss via linearity: pyr(p) - pyr(t) = pyr(p - t).
// R14: 2-way band interleave per wave. R13 forensics: L0 = ~5400 cyc/iter on
// a single dependent chain/wave (~1/SIMD) — per-iteration DMA-completion dead
// time has nothing to overlap it. Not demand-BW (R13: -15% bytes -> -3% time),
// not occupancy (R12: 57% occ slower), not bank conflicts (0). Fix: each wave
// runs TWO independent bands (separate 4-slot rings, interleaved stage order
// b0(r),b1(r) so in-order vmcnt counts stay exact: prologue 2*OPS, steady
// 4*OPS, drain 0). All per-band state statically [2]-indexed (unrolled).
// Compute algebra unchanged (R11/R13-validated, absmax 0). Tail: R13's
// 3-level per-image LDS pyramid (L2+L3+L4) + finish.

__device__ __forceinline__ int reflect_i(int m, int S) {
    if (m < 0) m = -m;
    if (m >= S) m = 2 * S - 2 - m;
    return m;
}

__device__ __forceinline__ void wg_barrier() {
    asm volatile("s_waitcnt lgkmcnt(0)" ::: "memory");
    __builtin_amdgcn_s_barrier();
}

#define LGKM0 asm volatile("s_waitcnt lgkmcnt(0)" ::: "memory")

template <int N>
__device__ __forceinline__ void wait_vm() {
    if constexpr (N == 0)       asm volatile("s_waitcnt vmcnt(0)" ::: "memory");
    else if constexpr (N == 2)  asm volatile("s_waitcnt vmcnt(2)" ::: "memory");
    else if constexpr (N == 4)  asm volatile("s_waitcnt vmcnt(4)" ::: "memory");
    else if constexpr (N == 8)  asm volatile("s_waitcnt vmcnt(8)" ::: "memory");
    else if constexpr (N == 16) asm volatile("s_waitcnt vmcnt(16)" ::: "memory");
}

__device__ __forceinline__ void gld16(const void* g, void* l) {
    __builtin_amdgcn_global_load_lds(
        (const __attribute__((address_space(1))) void*)g,
        (__attribute__((address_space(3))) void*)l, 16, 0, 0);
}

template <int S, int ISL0, int DH, int WPB>
__global__ __launch_bounds__(WPB * 64)
void pyr2_kernel(const float* __restrict__ a, const float* __restrict__ b,
                 float* __restrict__ dwn, float* __restrict__ acc, float scale) {
    constexpr int NB = 2;                         // bands per wave
    constexpr int D = S / 2;
    constexpr int CPL = S / 128;                  // down cols per lane: 4/2
    constexpr int ROWB = (CPL == 4) ? 2048 : 1024;
    constexpr int SLOT = ROWB * (ISL0 ? 2 : 1);
    constexpr int OPS = (CPL == 4) ? (ISL0 ? 4 : 2) : 1;  // gld16 per stage_row
    constexpr int NRS = D / DH;

    __shared__ float4 ringmem[WPB * NB * 4 * SLOT / 16];
    const int wv = threadIdx.x >> 6;
    const int lane = threadIdx.x & 63;
    char* ringw = (char*)ringmem + wv * (NB * 4 * SLOT);

    const int wid = blockIdx.x * WPB + wv;
    int R0[NB];
    size_t gbase[NB], dboff[NB];
    #pragma unroll
    for (int k = 0; k < NB; k++) {
        int g = wid * NB + k;
        int rs = g % NRS;
        int n = g / NRS;
        R0[k] = rs * DH;
        gbase[k] = (size_t)n * S * S;
        dboff[k] = (size_t)n * D * D;
    }

    auto stage_row = [&](int k, int s) {
        int gr = reflect_i(2 * R0[k] - 4 + s, S);
        const char* ga = (const char*)(a + gbase[k] + (size_t)gr * S);
        char* la = ringw + k * (4 * SLOT) + (s & 3) * SLOT;
        if constexpr (CPL == 4) {
            gld16(ga + 16 * lane, la);
            gld16(ga + 16 * lane + 1024, la + 1024);
        } else {
            gld16(ga + 16 * lane, la);
        }
        if constexpr (ISL0) {
            const char* gb = (const char*)(b + gbase[k] + (size_t)gr * S);
            gld16(gb + 16 * lane, la + ROWB);
            gld16(gb + 16 * lane + 1024, la + ROWB + 1024);
        }
    };

    // own-chunk reads + shuffle halos: c[2*CPL] lane's cur cols, h[CPL] h-tap
    auto proc_row = [&](int k, int s, float* c, float* h) {
        const char* pa = ringw + k * (4 * SLOT) + (s & 3) * SLOT;
        if constexpr (CPL == 4) {
            float4 x0 = *(const float4*)(pa + 16 * lane);           // cols 4l..
            float4 x1 = *(const float4*)(pa + 1024 + 16 * lane);    // cols 256+4l..
            if constexpr (ISL0) {
                const char* pb = pa + ROWB;
                float4 y0 = *(const float4*)(pb + 16 * lane);
                float4 y1 = *(const float4*)(pb + 1024 + 16 * lane);
                x0.x -= y0.x; x0.y -= y0.y; x0.z -= y0.z; x0.w -= y0.w;
                x1.x -= y1.x; x1.y -= y1.y; x1.z -= y1.z; x1.w -= y1.w;
            }
            c[0]=x0.x; c[1]=x0.y; c[2]=x0.z; c[3]=x0.w;
            c[4]=x1.x; c[5]=x1.y; c[6]=x1.z; c[7]=x1.w;
            float lu2  = __shfl_up(x0.z, 1, 64);
            float lu3  = __shfl_up(x0.w, 1, 64);
            float rd0  = __shfl_down(x0.x, 1, 64);
            float bcA  = __shfl(x1.x, 0, 64);      // col 256
            float lu2b = __shfl_up(x1.z, 1, 64);
            float lu3b = __shfl_up(x1.w, 1, 64);
            float rd0b = __shfl_down(x1.x, 1, 64);
            float bcZ  = __shfl(x0.z, 63, 64);     // col 254
            float bcW  = __shfl(x0.w, 63, 64);     // col 255
            float w0 = (lane == 0) ? x0.z : lu2;   // col 4l-2 (edge: 2)
            float w1 = (lane == 0) ? x0.y : lu3;   // col 4l-1 (edge: 1)
            float w6 = (lane == 63) ? bcA : rd0;   // col 4l+4 (boundary: 256)
            float v0 = (lane == 0) ? bcZ : lu2b;
            float v1 = (lane == 0) ? bcW : lu3b;
            float v6 = (lane == 63) ? x1.z : rd0b; // col 510 reflect
            h[0] = w0 + 4.f*w1 + 6.f*x0.x + 4.f*x0.y + x0.z;
            h[1] = x0.x + 4.f*x0.y + 6.f*x0.z + 4.f*x0.w + w6;
            h[2] = v0 + 4.f*v1 + 6.f*x1.x + 4.f*x1.y + x1.z;
            h[3] = x1.x + 4.f*x1.y + 6.f*x1.z + 4.f*x1.w + v6;
        } else {
            float4 x0 = *(const float4*)(pa + 16 * lane);
            c[0]=x0.x; c[1]=x0.y; c[2]=x0.z; c[3]=x0.w;
            float lu2 = __shfl_up(x0.z, 1, 64);
            float lu3 = __shfl_up(x0.w, 1, 64);
            float rd0 = __shfl_down(x0.x, 1, 64);
            float w0 = (lane == 0) ? x0.z : lu2;
            float w1 = (lane == 0) ? x0.y : lu3;
            float w6 = (lane == 63) ? x0.z : rd0;  // col S -> S-2 reflect
            h[0] = w0 + 4.f*w1 + 6.f*x0.x + 4.f*x0.y + x0.z;
            h[1] = x0.x + 4.f*x0.y + 6.f*x0.z + 4.f*x0.w + w6;
        }
    };

    float hA[NB][CPL], hB[NB][CPL], hC[NB][CPL], hD[NB][CPL], hE[NB][CPL];
    float cEv1[NB][2*CPL], cEv2[NB][2*CPL], cOd1[NB][2*CPL], dump[2*CPL];
    float ex0[NB][CPL] = {}, ex1[NB][CPL] = {}, ox0[NB][CPL] = {}, ox1[NB][CPL] = {};
    float sum = 0.f;

    // prologue: pairwise stage rows 0-3 both bands, proc rows 0-2, stage 4-6
    #pragma unroll
    for (int s = 0; s < 4; s++) { stage_row(0, s); stage_row(1, s); }
    wait_vm<2 * OPS>();                   // rows 0-2 of BOTH bands landed
    #pragma unroll
    for (int k = 0; k < NB; k++) {
        proc_row(k, 0, dump, hA[k]);
        proc_row(k, 1, dump, hB[k]);
        proc_row(k, 2, dump, hC[k]);
    }
    LGKM0;
    #pragma unroll
    for (int s = 4; s < 7; s++) { stage_row(0, s); stage_row(1, s); }

    #pragma unroll
    for (int j = 0; j <= DH + 1; ++j) {
        if (j <= DH) wait_vm<4 * OPS>(); else wait_vm<0>();

        float c3[NB][2*CPL], c4[NB][2*CPL];
        #pragma unroll
        for (int k = 0; k < NB; k++) {
            proc_row(k, 2 * j + 3, c3[k], hD[k]);
            proc_row(k, 2 * j + 4, c4[k], hE[k]);
        }

        #pragma unroll
        for (int k = 0; k < NB; k++) {
            const int m = R0[k] - 1 + j;
            float d[CPL], dl[CPL], dr[CPL], ex2[CPL], ox2[CPL];
            #pragma unroll
            for (int q = 0; q < CPL; q++)
                d[q] = (hA[k][q] + 4.f*hB[k][q] + 6.f*hC[k][q]
                      + 4.f*hD[k][q] + hE[k][q]) * (1.f / 256.f);

            if constexpr (CPL == 4) {
                float su1 = __shfl_up(d[1], 1, 64);
                float su3 = __shfl_up(d[3], 1, 64);
                float sd0 = __shfl_down(d[0], 1, 64);
                float sd2 = __shfl_down(d[2], 1, 64);
                float bc1 = __shfl(d[1], 63, 64);  // down col 127
                float bc2 = __shfl(d[2], 0, 64);   // down col 128
                dl[0] = (lane == 0) ? d[1] : su1;  // col -1 -> 1
                dl[1] = d[0];
                dl[2] = (lane == 0) ? bc1 : su3;
                dl[3] = d[2];
                dr[0] = d[1];
                dr[1] = (lane == 63) ? bc2 : sd0;
                dr[2] = d[3];
                dr[3] = (lane == 63) ? d[3] : sd2; // col D -> D-1
            } else {
                float su1 = __shfl_up(d[1], 1, 64);
                float sd0 = __shfl_down(d[0], 1, 64);
                dl[0] = (lane == 0) ? d[1] : su1;
                dl[1] = d[0];
                dr[0] = d[1];
                dr[1] = (lane == 63) ? d[1] : sd0;
            }
            #pragma unroll
            for (int q = 0; q < CPL; q++) {
                ex2[q] = 0.125f * (dl[q] + 6.f * d[q] + dr[q]);
                ox2[q] = 0.5f * (d[q] + dr[q]);
            }

            if (j >= 1 && j <= DH) {
                float* db = dwn + dboff[k];
                if constexpr (CPL == 4) {
                    *(float2*)(db + (size_t)m * D + 2 * lane) = make_float2(d[0], d[1]);
                    *(float2*)(db + (size_t)m * D + D / 2 + 2 * lane) = make_float2(d[2], d[3]);
                } else {
                    *(float2*)(db + (size_t)m * D + 2 * lane) = make_float2(d[0], d[1]);
                }
            }

            if (j >= 2) {
                const int me = m - 1;
                #pragma unroll
                for (int q = 0; q < CPL; q++) {
                    float eA = (me == 0) ? ex2[q] : ex0[k][q];     // row -1 -> 1
                    float oA = (me == 0) ? ox2[q] : ox0[k][q];
                    float eC = (me == D - 1) ? ex1[k][q] : ex2[q]; // row D -> D-1
                    float oC = (me == D - 1) ? ox1[k][q] : ox2[q];
                    float uee = 0.125f * (eA + 6.f * ex1[k][q] + eC);
                    float ueo = 0.125f * (oA + 6.f * ox1[k][q] + oC);
                    float uoe = 0.5f * (ex1[k][q] + eC);
                    float uoo = 0.5f * (ox1[k][q] + oC);
                    sum += fabsf(cEv2[k][2*q]   - uee) + fabsf(cEv2[k][2*q+1] - ueo)
                         + fabsf(cOd1[k][2*q]   - uoe) + fabsf(cOd1[k][2*q+1] - uoo);
                }
            }

            #pragma unroll
            for (int q = 0; q < CPL; q++) {
                ex0[k][q] = ex1[k][q]; ex1[k][q] = ex2[q];
                ox0[k][q] = ox1[k][q]; ox1[k][q] = ox2[q];
                hA[k][q] = hC[k][q]; hB[k][q] = hD[k][q]; hC[k][q] = hE[k][q];
            }
            #pragma unroll
            for (int q = 0; q < 2 * CPL; q++) {
                cEv2[k][q] = cEv1[k][q];
                cEv1[k][q] = c4[k][q];
                cOd1[k][q] = c3[k][q];
            }
        }

        if (j <= DH - 1) {
            LGKM0;                       // ds_reads retired before slot reuse
            stage_row(0, 2 * j + 7); stage_row(1, 2 * j + 7);
            stage_row(0, 2 * j + 8); stage_row(1, 2 * j + 8);
        }
    }

    #pragma unroll
    for (int o = 32; o > 0; o >>= 1) sum += __shfl_down(sum, o, 64);
    if (lane == 0) atomicAdd(&acc[wid & 63], sum * scale);
}

// ---- in-LDS level: cur (SxS resident) -> dn (DxD); partial |cur-up| sum ----
__device__ float level_in_lds(const float* cur, float* h, float* dn,
                              int S, int tid, int nt) {
    const int D = S >> 1;
    for (int i = tid; i < S * D; i += nt) {
        int r = i / D, xh = i % D;
        int c0 = reflect_i(2 * xh - 2, S), c1 = reflect_i(2 * xh - 1, S);
        int c3 = 2 * xh + 1, c4 = reflect_i(2 * xh + 2, S);
        const float* row = cur + r * S;
        h[i] = row[c0] + 4.f * row[c1] + 6.f * row[2 * xh] + 4.f * row[c3] + row[c4];
    }
    wg_barrier();
    for (int i = tid; i < D * D; i += nt) {
        int yh = i / D, xh = i % D;
        int r0 = reflect_i(2 * yh - 2, S), r1 = reflect_i(2 * yh - 1, S);
        int r3 = 2 * yh + 1, r4 = reflect_i(2 * yh + 2, S);
        dn[i] = (h[r0 * D + xh] + 4.f * h[r1 * D + xh] + 6.f * h[2 * yh * D + xh]
               + 4.f * h[r3 * D + xh] + h[r4 * D + xh]) * (1.f / 256.f);
    }
    wg_barrier();
    float sum = 0.f;
    for (int i = tid; i < D * D; i += nt) {
        int yh2 = i / D, q = i % D;
        int rm = (yh2 == 0) ? 1 : yh2 - 1;
        int rp = (yh2 == D - 1) ? D - 1 : yh2 + 1;
        int cm = (q == 0) ? 1 : q - 1;
        int cp = (q == D - 1) ? D - 1 : q + 1;
        float A00 = dn[rm * D + cm], A01 = dn[rm * D + q], A02 = dn[rm * D + cp];
        float A10 = dn[yh2 * D + cm], A11 = dn[yh2 * D + q], A12 = dn[yh2 * D + cp];
        float A20 = dn[rp * D + cm], A21 = dn[rp * D + q], A22 = dn[rp * D + cp];
        float ex0 = (A00 + 6.f * A01 + A02) * 0.125f;
        float ex1 = (A10 + 6.f * A11 + A12) * 0.125f;
        float ex2 = (A20 + 6.f * A21 + A22) * 0.125f;
        float ox0 = (A01 + A02) * 0.5f;
        float ox1 = (A11 + A12) * 0.5f;
        float ox2 = (A21 + A22) * 0.5f;
        float uee = (ex0 + 6.f * ex1 + ex2) * 0.125f;
        float ueo = (ox0 + 6.f * ox1 + ox2) * 0.125f;
        float uoe = (ex1 + ex2) * 0.5f;
        float uoo = (ox1 + ox2) * 0.5f;
        const float* c0 = cur + (2 * yh2) * S + 2 * q;
        sum += fabsf(c0[0] - uee) + fabsf(c0[1] - ueo)
             + fabsf(c0[S] - uoe) + fabsf(c0[S + 1] - uoo);
    }
    wg_barrier();
    return sum;
}

// levels 2+3+4 per image: dn1 (128x128) -> all in LDS (R6/R13-proven).
__global__ __launch_bounds__(512, 1)
void tail_kernel(const float* __restrict__ d1, float* __restrict__ acc,
                 float s2, float s3, float s4) {
    __shared__ float cur[128 * 128];
    __shared__ float hbuf[128 * 64];
    __shared__ float dn2[64 * 64];
    int n = blockIdx.x, tid = threadIdx.x;
    const int nt = 512;
    const float4* src = (const float4*)(d1 + (size_t)n * 128 * 128);
    for (int i = tid; i < 128 * 32; i += nt) ((float4*)cur)[i] = src[i];
    wg_barrier();
    float sum = level_in_lds(cur, hbuf, dn2, 128, tid, nt) * s2;
    float* dn3 = cur;
    sum += level_in_lds(dn2, hbuf, dn3, 64, tid, nt) * s3;
    float* dn4 = cur + 32 * 32;
    sum += level_in_lds(dn3, hbuf, dn4, 32, tid, nt) * s4;
    #pragma unroll
    for (int o = 32; o > 0; o >>= 1) sum += __shfl_down(sum, o, 64);
    __shared__ float s[8];
    int lane = tid & 63, w = tid >> 6;
    if (lane == 0) s[w] = sum;
    wg_barrier();
    if (tid == 0) {
        float v = 0.f;
        #pragma unroll
        for (int i = 0; i < 8; i++) v += s[i];
        atomicAdd(&acc[n & 63], v);
    }
}

__global__ void finish_kernel(const float* __restrict__ acc, float* __restrict__ out) {
    float v = acc[threadIdx.x];
    #pragma unroll
    for (int o = 32; o > 0; o >>= 1) v += __shfl_down(v, o, 64);
    if (threadIdx.x == 0) out[0] = v;
}

extern "C" void kernel_launch(void* const* d_in, const int* in_sizes, int n_in,
                              void* d_out, int out_size, void* d_ws, size_t ws_size,
                              hipStream_t stream) {
    const float* p = (const float*)d_in[0];
    const float* t = (const float*)d_in[1];
    float* out = (float*)d_out;
    float* acc = (float*)d_ws;                    // 64 accumulator slots
    float* dn0 = acc + 64;                        // 48 * 256 * 256
    float* dn1 = dn0 + (size_t)48 * 256 * 256;    // 48 * 128 * 128

    hipMemsetAsync(acc, 0, 64 * sizeof(float), stream);

    const int N = 48;  // 16 batch * 3 channels (depthwise)

    // L0: D=256, DH=8 -> 1536 bands, 2/wave -> 768 waves, WPB=2 -> 384 blocks
    pyr2_kernel<512, 1, 8, 2><<<384, 128, 0, stream>>>(
        p, t, dn0, acc, 1.f / (float)(N * 512 * 512));
    // L1: D=128, DH=8 -> 768 bands, 2/wave -> 384 waves, WPB=4 -> 96 blocks
    pyr2_kernel<256, 0, 8, 4><<<96, 256, 0, stream>>>(
        dn0, nullptr, dn1, acc, 2.f / (float)(N * 256 * 256));
    // L2+L3+L4: one block per image, fully LDS-resident
    tail_kernel<<<N, 512, 0, stream>>>(dn1, acc,
                                       4.f / (float)(N * 128 * 128),
                                       8.f / (float)(N * 64 * 64),
                                       16.f / (float)(N * 32 * 32));
    finish_kernel<<<1, 64, 0, stream>>>(acc, out);
}

// Round 15
// 59.034 us; speedup vs baseline: 1.0240x; 1.0240x over previous
//
#include <hip/hip_runtime.h>

// Laplacian pyramid loss via linearity: pyr(p) - pyr(t) = pyr(p - t).
// R15: revert to R13 (best: 57.2us) + one trim: L1 DH 8->16 (halo demand
// 1.31x -> 1.16x, same lever as L0's R13 win). CEILING EVIDENCE (R9-R14):
// five distinct L0 structures pin at 40+-3us = ~113MB demand / ~2.9 TB/s,
// which matches the per-direction read delivery rate (m13 "6.29 TB/s copy"
// is read+write summed; fill hits 6.9 TB/s pure-write). Killed hypotheses:
// demand-BW (-15% bytes -> -3% time), occupancy (57% slower than 7%),
// bytes-in-flight (287KB/CU in flight -> still 2.3 TB/s), bank conflicts
// (0 -> same), DMA-addr swizzle (linear==swizzled), chain-serialization
// (2 chains/wave null: joint in-order vmcnt).

__device__ __forceinline__ int reflect_i(int m, int S) {
    if (m < 0) m = -m;
    if (m >= S) m = 2 * S - 2 - m;
    return m;
}

__device__ __forceinline__ void wg_barrier() {
    asm volatile("s_waitcnt lgkmcnt(0)" ::: "memory");
    __builtin_amdgcn_s_barrier();
}

#define LGKM0 asm volatile("s_waitcnt lgkmcnt(0)" ::: "memory")

template <int N>
__device__ __forceinline__ void wait_vm() {
    if constexpr (N == 0)      asm volatile("s_waitcnt vmcnt(0)" ::: "memory");
    else if constexpr (N == 1) asm volatile("s_waitcnt vmcnt(1)" ::: "memory");
    else if constexpr (N == 2) asm volatile("s_waitcnt vmcnt(2)" ::: "memory");
    else if constexpr (N == 4) asm volatile("s_waitcnt vmcnt(4)" ::: "memory");
    else if constexpr (N == 8) asm volatile("s_waitcnt vmcnt(8)" ::: "memory");
}

__device__ __forceinline__ void gld16(const void* g, void* l) {
    __builtin_amdgcn_global_load_lds(
        (const __attribute__((address_space(1))) void*)g,
        (__attribute__((address_space(3))) void*)l, 16, 0, 0);
}

template <int S, int ISL0, int DH, int WPB>
__global__ __launch_bounds__(WPB * 64, 2)
void pyr_kernel(const float* __restrict__ a, const float* __restrict__ b,
                float* __restrict__ dwn, float* __restrict__ acc, float scale) {
    constexpr int D = S / 2;
    constexpr int CPL = S / 128;                  // down cols per lane: 4/2/1
    constexpr int ROWB = (CPL == 4) ? 2048 : 1024;
    constexpr int SLOT = ROWB * (ISL0 ? 2 : 1);
    constexpr int OPS = (CPL == 4) ? (ISL0 ? 4 : 2) : 1;  // gld16 per stage_row
    constexpr int NRS = D / DH;

    __shared__ float4 ringmem[WPB * 4 * SLOT / 16]; // WPB waves x 4 slots
    const int wv = threadIdx.x >> 6;
    const int lane = threadIdx.x & 63;
    char* ring = (char*)ringmem + wv * (4 * SLOT);

    const int wid = blockIdx.x * WPB + wv;
    const int rs = wid % NRS;
    const int n = wid / NRS;
    const int R0 = rs * DH;
    const size_t gbase = (size_t)n * S * S;

    auto stage_row = [&](int s) {
        int gr = reflect_i(2 * R0 - 4 + s, S);
        const char* ga = (const char*)(a + gbase + (size_t)gr * S);
        char* la = ring + (s & 3) * SLOT;
        if constexpr (CPL == 4) {
            gld16(ga + 16 * lane, la);
            gld16(ga + 16 * lane + 1024, la + 1024);
        } else if constexpr (CPL == 2) {
            gld16(ga + 16 * lane, la);
        } else {
            gld16(ga + 16 * (lane & 31), la);    // 512B row; lanes>=32 dup pad
        }
        if constexpr (ISL0) {
            const char* gb = (const char*)(b + gbase + (size_t)gr * S);
            gld16(gb + 16 * lane, la + ROWB);
            gld16(gb + 16 * lane + 1024, la + ROWB + 1024);
        }
    };

    // own-chunk reads + shuffle halos; fills c[2*CPL] (lane's cur cols) and
    // h[CPL] (horizontal 5-tap at the lane's down cols).
    auto proc_row = [&](int s, float* c, float* h) {
        const char* pa = ring + (s & 3) * SLOT;
        if constexpr (CPL == 4) {
            float4 x0 = *(const float4*)(pa + 16 * lane);           // cols 4l..
            float4 x1 = *(const float4*)(pa + 1024 + 16 * lane);    // cols 256+4l..
            if constexpr (ISL0) {
                const char* pb = pa + ROWB;
                float4 y0 = *(const float4*)(pb + 16 * lane);
                float4 y1 = *(const float4*)(pb + 1024 + 16 * lane);
                x0.x -= y0.x; x0.y -= y0.y; x0.z -= y0.z; x0.w -= y0.w;
                x1.x -= y1.x; x1.y -= y1.y; x1.z -= y1.z; x1.w -= y1.w;
            }
            c[0]=x0.x; c[1]=x0.y; c[2]=x0.z; c[3]=x0.w;
            c[4]=x1.x; c[5]=x1.y; c[6]=x1.z; c[7]=x1.w;
            float lu2  = __shfl_up(x0.z, 1, 64);
            float lu3  = __shfl_up(x0.w, 1, 64);
            float rd0  = __shfl_down(x0.x, 1, 64);
            float bcA  = __shfl(x1.x, 0, 64);     // col 256
            float lu2b = __shfl_up(x1.z, 1, 64);
            float lu3b = __shfl_up(x1.w, 1, 64);
            float rd0b = __shfl_down(x1.x, 1, 64);
            float bcZ  = __shfl(x0.z, 63, 64);    // col 254
            float bcW  = __shfl(x0.w, 63, 64);    // col 255
            float w0 = (lane == 0) ? x0.z : lu2;  // col 4l-2 (edge: col 2)
            float w1 = (lane == 0) ? x0.y : lu3;  // col 4l-1 (edge: col 1)
            float w6 = (lane == 63) ? bcA : rd0;  // col 4l+4 (boundary: 256)
            float v0 = (lane == 0) ? bcZ : lu2b;  // col 256+4l-2
            float v1 = (lane == 0) ? bcW : lu3b;  // col 256+4l-1
            float v6 = (lane == 63) ? x1.z : rd0b; // col 510 reflect
            h[0] = w0 + 4.f*w1 + 6.f*x0.x + 4.f*x0.y + x0.z;
            h[1] = x0.x + 4.f*x0.y + 6.f*x0.z + 4.f*x0.w + w6;
            h[2] = v0 + 4.f*v1 + 6.f*x1.x + 4.f*x1.y + x1.z;
            h[3] = x1.x + 4.f*x1.y + 6.f*x1.z + 4.f*x1.w + v6;
        } else if constexpr (CPL == 2) {
            float4 x0 = *(const float4*)(pa + 16 * lane);
            c[0]=x0.x; c[1]=x0.y; c[2]=x0.z; c[3]=x0.w;
            float lu2 = __shfl_up(x0.z, 1, 64);
            float lu3 = __shfl_up(x0.w, 1, 64);
            float rd0 = __shfl_down(x0.x, 1, 64);
            float w0 = (lane == 0) ? x0.z : lu2;
            float w1 = (lane == 0) ? x0.y : lu3;
            float w6 = (lane == 63) ? x0.z : rd0;  // col S -> S-2 reflect
            h[0] = w0 + 4.f*w1 + 6.f*x0.x + 4.f*x0.y + x0.z;
            h[1] = x0.x + 4.f*x0.y + 6.f*x0.z + 4.f*x0.w + w6;
        } else {
            float2 x0 = *(const float2*)(pa + 8 * lane);  // cols 2l, 2l+1
            c[0]=x0.x; c[1]=x0.y;
            float lu0 = __shfl_up(x0.x, 1, 64);
            float lu1 = __shfl_up(x0.y, 1, 64);
            float rd0 = __shfl_down(x0.x, 1, 64);
            float w0 = (lane == 0) ? rd0 : lu0;    // col 2l-2 (edge: col 2)
            float w1 = (lane == 0) ? x0.y : lu1;   // col 2l-1 (edge: col 1)
            float w4 = (lane == 63) ? x0.x : rd0;  // col 2l+2 (edge: S-2)
            h[0] = w0 + 4.f*w1 + 6.f*x0.x + 4.f*x0.y + w4;
        }
    };

    float hA[CPL], hB[CPL], hC[CPL], hD[CPL], hE[CPL];
    float cEv1[2*CPL], cEv2[2*CPL], cOd1[2*CPL], dump[2*CPL];
    float ex0[CPL] = {}, ex1[CPL] = {}, ox0[CPL] = {}, ox1[CPL] = {};
    float sum = 0.f;
    float* dbase = dwn + (size_t)n * D * D;

    // prologue: fill 4 slots, h for rows 0-2, refill freed slots with 4-6
    stage_row(0); stage_row(1); stage_row(2); stage_row(3);
    wait_vm<OPS>();                       // rows 0-2 landed (row 3 may fly)
    proc_row(0, dump, hA);
    proc_row(1, dump, hB);
    proc_row(2, dump, hC);
    LGKM0;
    stage_row(4); stage_row(5); stage_row(6);

    #pragma unroll
    for (int j = 0; j <= DH + 1; ++j) {
        const int m = R0 - 1 + j;
        if (j <= DH) wait_vm<2 * OPS>(); else wait_vm<0>();

        float c3[2*CPL], c4[2*CPL];
        proc_row(2 * j + 3, c3, hD);
        proc_row(2 * j + 4, c4, hE);

        float d[CPL], dl[CPL], dr[CPL], ex2[CPL], ox2[CPL];
        #pragma unroll
        for (int q = 0; q < CPL; q++)
            d[q] = (hA[q] + 4.f*hB[q] + 6.f*hC[q] + 4.f*hD[q] + hE[q]) * (1.f / 256.f);

        if constexpr (CPL == 4) {
            float su1 = __shfl_up(d[1], 1, 64);    // down col 2l-1
            float su3 = __shfl_up(d[3], 1, 64);    // down col 127+2l
            float sd0 = __shfl_down(d[0], 1, 64);  // down col 2l+2
            float sd2 = __shfl_down(d[2], 1, 64);  // down col 130+2l
            float bc1 = __shfl(d[1], 63, 64);      // down col 127
            float bc2 = __shfl(d[2], 0, 64);       // down col 128
            dl[0] = (lane == 0) ? d[1] : su1;      // col -1 -> 1
            dl[1] = d[0];
            dl[2] = (lane == 0) ? bc1 : su3;
            dl[3] = d[2];
            dr[0] = d[1];
            dr[1] = (lane == 63) ? bc2 : sd0;
            dr[2] = d[3];
            dr[3] = (lane == 63) ? d[3] : sd2;     // col D -> D-1
        } else if constexpr (CPL == 2) {
            float su1 = __shfl_up(d[1], 1, 64);
            float sd0 = __shfl_down(d[0], 1, 64);
            dl[0] = (lane == 0) ? d[1] : su1;
            dl[1] = d[0];
            dr[0] = d[1];
            dr[1] = (lane == 63) ? d[1] : sd0;
        } else {
            float su = __shfl_up(d[0], 1, 64);
            float sd = __shfl_down(d[0], 1, 64);
            dl[0] = (lane == 0) ? sd : su;
            dr[0] = (lane == 63) ? d[0] : sd;
        }
        #pragma unroll
        for (int q = 0; q < CPL; q++) {
            ex2[q] = 0.125f * (dl[q] + 6.f * d[q] + dr[q]);
            ox2[q] = 0.5f * (d[q] + dr[q]);
        }

        if (j >= 1 && j <= DH) {
            if constexpr (CPL == 4) {
                *(float2*)(dbase + (size_t)m * D + 2 * lane) = make_float2(d[0], d[1]);
                *(float2*)(dbase + (size_t)m * D + D / 2 + 2 * lane) = make_float2(d[2], d[3]);
            } else if constexpr (CPL == 2) {
                *(float2*)(dbase + (size_t)m * D + 2 * lane) = make_float2(d[0], d[1]);
            } else {
                dbase[(size_t)m * D + lane] = d[0];
            }
        }

        if (j >= 2) {
            const int me = m - 1;
            #pragma unroll
            for (int q = 0; q < CPL; q++) {
                float eA = (me == 0) ? ex2[q] : ex0[q];       // down row -1 -> 1
                float oA = (me == 0) ? ox2[q] : ox0[q];
                float eC = (me == D - 1) ? ex1[q] : ex2[q];   // down row D -> D-1
                float oC = (me == D - 1) ? ox1[q] : ox2[q];
                float uee = 0.125f * (eA + 6.f * ex1[q] + eC);
                float ueo = 0.125f * (oA + 6.f * ox1[q] + oC);
                float uoe = 0.5f * (ex1[q] + eC);
                float uoo = 0.5f * (ox1[q] + oC);
                sum += fabsf(cEv2[2*q]   - uee) + fabsf(cEv2[2*q+1] - ueo)
                     + fabsf(cOd1[2*q]   - uoe) + fabsf(cOd1[2*q+1] - uoo);
            }
        }

        #pragma unroll
        for (int q = 0; q < CPL; q++) {
            ex0[q] = ex1[q]; ex1[q] = ex2[q];
            ox0[q] = ox1[q]; ox1[q] = ox2[q];
            hA[q] = hC[q]; hB[q] = hD[q]; hC[q] = hE[q];
        }
        #pragma unroll
        for (int q = 0; q < 2 * CPL; q++) {
            cEv2[q] = cEv1[q];          // cur row seq 2j (even lap row)
            cEv1[q] = c4[q];            // seq 2j+4 -> lap @ j+2
            cOd1[q] = c3[q];            // seq 2j+3 -> lap @ j+1
        }

        if (j <= DH - 1) {
            LGKM0;                      // ds_reads retired before slot reuse
            stage_row(2 * j + 7);
            stage_row(2 * j + 8);
        }
    }

    #pragma unroll
    for (int o = 32; o > 0; o >>= 1) sum += __shfl_down(sum, o, 64);
    if (lane == 0) atomicAdd(&acc[wid & 63], sum * scale);
}

// ---- in-LDS level: cur (SxS resident) -> dn (DxD); partial |cur-up| sum ----
__device__ float level_in_lds(const float* cur, float* h, float* dn,
                              int S, int tid, int nt) {
    const int D = S >> 1;
    for (int i = tid; i < S * D; i += nt) {
        int r = i / D, xh = i % D;
        int c0 = reflect_i(2 * xh - 2, S), c1 = reflect_i(2 * xh - 1, S);
        int c3 = 2 * xh + 1, c4 = reflect_i(2 * xh + 2, S);
        const float* row = cur + r * S;
        h[i] = row[c0] + 4.f * row[c1] + 6.f * row[2 * xh] + 4.f * row[c3] + row[c4];
    }
    wg_barrier();
    for (int i = tid; i < D * D; i += nt) {
        int yh = i / D, xh = i % D;
        int r0 = reflect_i(2 * yh - 2, S), r1 = reflect_i(2 * yh - 1, S);
        int r3 = 2 * yh + 1, r4 = reflect_i(2 * yh + 2, S);
        dn[i] = (h[r0 * D + xh] + 4.f * h[r1 * D + xh] + 6.f * h[2 * yh * D + xh]
               + 4.f * h[r3 * D + xh] + h[r4 * D + xh]) * (1.f / 256.f);
    }
    wg_barrier();
    float sum = 0.f;
    for (int i = tid; i < D * D; i += nt) {
        int yh2 = i / D, q = i % D;
        int rm = (yh2 == 0) ? 1 : yh2 - 1;
        int rp = (yh2 == D - 1) ? D - 1 : yh2 + 1;
        int cm = (q == 0) ? 1 : q - 1;
        int cp = (q == D - 1) ? D - 1 : q + 1;
        float A00 = dn[rm * D + cm], A01 = dn[rm * D + q], A02 = dn[rm * D + cp];
        float A10 = dn[yh2 * D + cm], A11 = dn[yh2 * D + q], A12 = dn[yh2 * D + cp];
        float A20 = dn[rp * D + cm], A21 = dn[rp * D + q], A22 = dn[rp * D + cp];
        float ex0 = (A00 + 6.f * A01 + A02) * 0.125f;
        float ex1 = (A10 + 6.f * A11 + A12) * 0.125f;
        float ex2 = (A20 + 6.f * A21 + A22) * 0.125f;
        float ox0 = (A01 + A02) * 0.5f;
        float ox1 = (A11 + A12) * 0.5f;
        float ox2 = (A21 + A22) * 0.5f;
        float uee = (ex0 + 6.f * ex1 + ex2) * 0.125f;
        float ueo = (ox0 + 6.f * ox1 + ox2) * 0.125f;
        float uoe = (ex1 + ex2) * 0.5f;
        float uoo = (ox1 + ox2) * 0.5f;
        const float* c0 = cur + (2 * yh2) * S + 2 * q;
        sum += fabsf(c0[0] - uee) + fabsf(c0[1] - ueo)
             + fabsf(c0[S] - uoe) + fabsf(c0[S + 1] - uoo);
    }
    wg_barrier();
    return sum;
}

// levels 2+3+4 per image: dn1 (128x128) -> all in LDS (R6/R13-proven).
__global__ __launch_bounds__(512, 1)
void tail_kernel(const float* __restrict__ d1, float* __restrict__ acc,
                 float s2, float s3, float s4) {
    __shared__ float cur[128 * 128];   // 64 KB; later reused for dn3, dn4
    __shared__ float hbuf[128 * 64];   // 32 KB; reused per level
    __shared__ float dn2[64 * 64];     // 16 KB
    int n = blockIdx.x, tid = threadIdx.x;
    const int nt = 512;
    const float4* src = (const float4*)(d1 + (size_t)n * 128 * 128);
    for (int i = tid; i < 128 * 32; i += nt) ((float4*)cur)[i] = src[i];
    wg_barrier();
    float sum = level_in_lds(cur, hbuf, dn2, 128, tid, nt) * s2;
    float* dn3 = cur;                  // 32*32, cur data now dead
    sum += level_in_lds(dn2, hbuf, dn3, 64, tid, nt) * s3;
    float* dn4 = cur + 32 * 32;        // 16*16
    sum += level_in_lds(dn3, hbuf, dn4, 32, tid, nt) * s4;
    #pragma unroll
    for (int o = 32; o > 0; o >>= 1) sum += __shfl_down(sum, o, 64);
    __shared__ float s[8];
    int lane = tid & 63, w = tid >> 6;
    if (lane == 0) s[w] = sum;
    wg_barrier();
    if (tid == 0) {
        float v = 0.f;
        #pragma unroll
        for (int i = 0; i < 8; i++) v += s[i];
        atomicAdd(&acc[n & 63], v);
    }
}

__global__ void finish_kernel(const float* __restrict__ acc, float* __restrict__ out) {
    float v = acc[threadIdx.x];
    #pragma unroll
    for (int o = 32; o > 0; o >>= 1) v += __shfl_down(v, o, 64);
    if (threadIdx.x == 0) out[0] = v;
}

extern "C" void kernel_launch(void* const* d_in, const int* in_sizes, int n_in,
                              void* d_out, int out_size, void* d_ws, size_t ws_size,
                              hipStream_t stream) {
    const float* p = (const float*)d_in[0];
    const float* t = (const float*)d_in[1];
    float* out = (float*)d_out;
    float* acc = (float*)d_ws;                    // 64 accumulator slots
    float* dn0 = acc + 64;                        // 48 * 256 * 256
    float* dn1 = dn0 + (size_t)48 * 256 * 256;    // 48 * 128 * 128

    hipMemsetAsync(acc, 0, 64 * sizeof(float), stream);

    const int N = 48;  // 16 batch * 3 channels (depthwise)

    // L0: D=256, DH=16 -> 16 bands/img, 768 waves, WPB=2 -> 384 blocks
    pyr_kernel<512, 1, 16, 2><<<384, 128, 0, stream>>>(
        p, t, dn0, acc, 1.f / (float)(N * 512 * 512));
    // L1: D=128, DH=16 -> 8 bands/img, 384 waves, WPB=4 -> 96 blocks
    pyr_kernel<256, 0, 16, 4><<<96, 256, 0, stream>>>(
        dn0, nullptr, dn1, acc, 2.f / (float)(N * 256 * 256));
    // L2+L3+L4: one block per image, fully LDS-resident (R6-proven)
    tail_kernel<<<N, 512, 0, stream>>>(dn1, acc,
                                       4.f / (float)(N * 128 * 128),
                                       8.f / (float)(N * 64 * 64),
                                       16.f / (float)(N * 32 * 32));
    finish_kernel<<<1, 64, 0, stream>>>(acc, out);
}